// Round 20
// baseline (191.132 us; speedup 1.0000x reference)
//
#include <hip/hip_runtime.h>
#include <hip/hip_bf16.h>
#include <stdint.h>

#define T_N  2048
#define HID  2048
#define NH   16
#define DN   128
#define DR   64
#define DV   128
#define KVD  512
#define DQK  192      // DN+DR
#define QDIM 3072     // NH*DQK
#define KVBD 4096     // NH*(DN+DV)
#define KVA  576      // KVD+DR
#define QKVN 3712     // fused q(3072) + kv_a(640 padded)
#define QBLK 128
#define KVBLK 64
#define TPH  40       // chunk-tasks per head

typedef short  s16x8 __attribute__((ext_vector_type(8)));
typedef float  f32x4 __attribute__((ext_vector_type(4)));
typedef unsigned short u16;
typedef unsigned short u16x2 __attribute__((ext_vector_type(2)));
typedef unsigned short u16x4 __attribute__((ext_vector_type(4)));

#define NEG_INF (-__builtin_inff())
#define AS1 __attribute__((address_space(1)))
#define AS3 __attribute__((address_space(3)))
__device__ __constant__ float SCALE_C = 0.07216878364870323f; // 192^-0.5

__device__ __forceinline__ u16 f2b(float f) {
  unsigned u = __float_as_uint(f);
  u += 0x7fffu + ((u >> 16) & 1u);
  return (u16)(u >> 16);
}
__device__ __forceinline__ float b2f(u16 v) {
  return __uint_as_float(((unsigned)v) << 16);
}

// ---------------- prep: hs cast + trig tables + wqkvT transpose ----------------
#define TQK (QKVN / 32)                          // 116
#define NBC 4096                                 // cast blocks
#define NBT 256                                  // table blocks
#define NB0 (TQK * (HID / 32))                   // 7424 (wqkvT)
#define NB1 ((KVBD / 32) * (KVD / 32))           // 2048 (wkvbT, fused into qkva GEMM)
#define NB2 ((HID / 32) * ((NH * DV) / 32))      // 4096 (woT, fused into qkva GEMM)
__global__ __launch_bounds__(256) void prep_all(
    const float* __restrict__ hs, u16* __restrict__ hsb,
    const int* __restrict__ pos, float* __restrict__ ctab, float* __restrict__ stab,
    const float* __restrict__ wq, const float* __restrict__ wkva,
    u16* __restrict__ wqkvT)
{
  int bid = blockIdx.x;
  const int tid = threadIdx.x;
  if (bid < NBC) {                       // cast: T_N*HID/4 float4 groups
    int i = bid * 256 + tid;
    float4 v = ((const float4*)hs)[i];
    u16x4 o;
    o.x = f2b(v.x); o.y = f2b(v.y); o.z = f2b(v.z); o.w = f2b(v.w);
    ((u16x4*)hsb)[i] = o;
    return;
  }
  if (bid < NBC + NBT) {                 // tables: T_N*32 entries
    int i = (bid - NBC) * 256 + tid;
    int t = i >> 5, j = i & 31;
    float inv = powf(10000.f, -(float)(2 * j) / 64.f);
    float f = (float)pos[t] * inv;
    float s, c;
    sincosf(f, &s, &c);
    ctab[i] = c; stab[i] = s;
    return;
  }
  bid -= NBC + NBT;                      // wqkvT transpose
  __shared__ float tile[32][33];
  const int tx = tid & 31, ty = tid >> 5;
  const int n0 = (bid % TQK) * 32, k0 = (bid / TQK) * 32;
#pragma unroll
  for (int i = 0; i < 4; ++i) {
    const int n = n0 + tx, k = k0 + ty + i * 8;
    float val;
    if (n < QDIM) val = wq[(size_t)k * QDIM + n];
    else { int n2 = n - QDIM; val = (n2 < KVA) ? wkva[(size_t)k * KVA + n2] : 0.f; }
    tile[ty + i * 8][tx] = val;
  }
  __syncthreads();
#pragma unroll
  for (int i = 0; i < 4; ++i)
    wqkvT[(size_t)(n0 + ty + i * 8) * HID + k0 + tx] = f2b(tile[tx][ty + i * 8]);
}

// ---------------- bf16 GEMM: TM x 128 tiles, BK=32 double-buffered, swizzled LDS ----
// MODE 0: C float. MODE 1: qkva — q cols roped+scaled straight to qf, kva cols to
//         compact kvab[T][640]; + overflow transpose blocks (wkvb->wkvbT, wo->woT).
// MODE 2: kv_b epilogue -> kf (nope half) + vT (v half). TM = 128 or 64 (M-tile).
template <int MODE, int TM>
__global__ __launch_bounds__(256) void gemm_bf16(
    const u16* __restrict__ A, const u16* __restrict__ Bt,
    void* __restrict__ Cout, u16* __restrict__ vT,
    const float* __restrict__ xw1, const float* __restrict__ xw2,
    u16* __restrict__ xd1, u16* __restrict__ xd2,
    const float* __restrict__ ctp, const float* __restrict__ stp,
    u16* __restrict__ qfo,
    int M, int N, int K)
{
  constexpr int ASZ = TM * 32;                     // A-buf u16 count (2048 or 4096)
  constexpr int MFR = TM / 32;                     // m-frags per wave (2 or 4)
  __shared__ __align__(16) u16 LDSu[2][ASZ + 4096];
  const int tid  = threadIdx.x;
  const int gx   = N >> 7;
  const int nwg  = (M / TM) * gx;

  if constexpr (MODE == 1) {
    // overflow blocks: wkvb / wo transposes, run on spare CUs while GEMM computes
    if ((int)blockIdx.x >= nwg) {
      float (*tile)[33] = reinterpret_cast<float(*)[33]>(&LDSu[0][0]);
      int b = (int)blockIdx.x - nwg;
      const float* src; u16* dst; int n0t, k0t, Kt, Nt;
      if (b < NB1) { n0t = (b % (KVBD/32)) * 32; k0t = (b / (KVBD/32)) * 32; Kt = KVD;   Nt = KVBD; src = xw1; dst = xd1; }
      else { b -= NB1; n0t = (b % (HID/32)) * 32;  k0t = (b / (HID/32)) * 32;  Kt = NH*DV; Nt = HID;  src = xw2; dst = xd2; }
      const int tx = tid & 31, ty = tid >> 5;
#pragma unroll
      for (int i = 0; i < 4; ++i)
        tile[ty + i * 8][tx] = src[(size_t)(k0t + ty + i * 8) * Nt + n0t + tx];
      __syncthreads();
#pragma unroll
      for (int i = 0; i < 4; ++i)
        dst[(size_t)(n0t + ty + i * 8) * Kt + k0t + tx] = f2b(tile[tx][ty + i * 8]);
      return;
    }
  }

  const int lane = tid & 63;
  const int w    = tid >> 6;
  int id = blockIdx.x;
  id = (id & 7) * (nwg >> 3) + (id >> 3);           // bijective XCD swizzle (nwg%8==0)
  const int m0 = (id / gx) * TM, n0 = (id % gx) * 128;

  const int wm = (w >> 1) * (TM / 2), wn = (w & 1) * 64;

  const int r0   = tid >> 2;                          // 0..63
  const int selE = (((tid & 3) ^ (r0 & 3)) << 3);     // element col within 32
  const u16* sA = A  + (size_t)(m0 + r0) * K + selE;
  const u16* sB = Bt + (size_t)(n0 + r0) * K + selE;
  const int ldsOff = tid * 8;                          // u16 units

  f32x4 acc[MFR][4];
  const f32x4 zero = {0.f, 0.f, 0.f, 0.f};
#pragma unroll
  for (int m = 0; m < MFR; ++m)
#pragma unroll
    for (int n = 0; n < 4; ++n) acc[m][n] = zero;

  const int arow = lane & 15;
  const int kb   = (lane >> 4) * 16;
  const int KT = K >> 5;

  auto stage = [&](int buf, int kt) {
    const int ko = kt << 5;
#pragma unroll
    for (int j = 0; j < TM / 64; ++j)
      __builtin_amdgcn_global_load_lds((const AS1 unsigned*)(sA + ko + (size_t)j * 64 * K),
                                       (AS3 unsigned*)(&LDSu[buf][ldsOff + j * 2048]), 16, 0, 0);
#pragma unroll
    for (int j = 0; j < 2; ++j)
      __builtin_amdgcn_global_load_lds((const AS1 unsigned*)(sB + ko + (size_t)j * 64 * K),
                                       (AS3 unsigned*)(&LDSu[buf][ASZ + ldsOff + j * 2048]), 16, 0, 0);
  };
  auto compute = [&](int buf) {
    const char* Ab = (const char*)&LDSu[buf][0];
    const char* Bb = (const char*)&LDSu[buf][ASZ];
    s16x8 af[MFR], bfr[4];
#pragma unroll
    for (int m = 0; m < MFR; ++m) {
      const int r = wm + m * 16 + arow;
      af[m] = *(const s16x8*)(Ab + r * 64 + (kb ^ ((r & 3) << 4)));
    }
#pragma unroll
    for (int n = 0; n < 4; ++n) {
      const int r = wn + n * 16 + arow;
      bfr[n] = *(const s16x8*)(Bb + r * 64 + (kb ^ ((r & 3) << 4)));
    }
#pragma unroll
    for (int m = 0; m < MFR; ++m)
#pragma unroll
      for (int n = 0; n < 4; ++n)
        acc[m][n] = __builtin_amdgcn_mfma_f32_16x16x32_bf16(af[m], bfr[n], acc[m][n], 0, 0, 0);
  };

  stage(0, 0);
  for (int kt = 0; kt < KT; kt += 2) {
    __syncthreads();
    stage(1, kt + 1);
    compute(0);
    __syncthreads();
    if (kt + 2 < KT) stage(0, kt + 2);
    compute(1);
  }

  const int r0w = (lane >> 4) * 4;
  const int cc = lane & 15;
  if constexpr (MODE == 2) {
    const int h = n0 >> 8;
    const bool vhalf = (n0 >> 7) & 1;
    u16* kf = (u16*)Cout;
#pragma unroll
    for (int m = 0; m < MFR; ++m)
#pragma unroll
      for (int n = 0; n < 4; ++n) {
        const int d = wn + n * 16 + cc;
        const int trow = m0 + wm + m * 16 + r0w;
        if (!vhalf) {
#pragma unroll
          for (int r = 0; r < 4; ++r)
            kf[(size_t)(trow + r) * QDIM + h * DQK + d] = f2b(acc[m][n][r]);
        } else {
          u16x4 o;
          o.x = f2b(acc[m][n][0]); o.y = f2b(acc[m][n][1]);
          o.z = f2b(acc[m][n][2]); o.w = f2b(acc[m][n][3]);
          *(u16x4*)&vT[((size_t)h * 128 + d) * T_N + trow] = o;
        }
      }
  } else if constexpr (MODE == 1) {
    if (n0 < QDIM) {
      // q region: rope (pe cols, pair via adjacent-lane shfl) + scale -> qf
      const float SC = SCALE_C;
#pragma unroll
      for (int m = 0; m < MFR; ++m)
#pragma unroll
        for (int n = 0; n < 4; ++n) {
          const int col = n0 + wn + n * 16 + cc;
          const int hh = col / DQK;
          const int d  = col - hh * DQK;
          const int trow = m0 + wm + m * 16 + r0w;
          if (d < 128) {
#pragma unroll
            for (int r = 0; r < 4; ++r)
              qfo[((size_t)(trow + r) * NH + hh) * DQK + d] = f2b(acc[m][n][r] * SC);
          } else {
            const int jj = (d - 128) >> 1;
            const float sgn = (d & 1) ? 1.f : -1.f;   // pairs never straddle d=128/head edge
#pragma unroll
            for (int r = 0; r < 4; ++r) {
              float v  = acc[m][n][r];
              float vp = __shfl_xor(v, 1, 64);        // partner col (even<->odd)
              const int t = trow + r;
              float cv = ctp[t * 32 + jj], sv = stp[t * 32 + jj];
              qfo[((size_t)t * NH + hh) * DQK + d] = f2b((v * cv + sgn * vp * sv) * SC);
            }
          }
        }
    } else {
      // kva region -> compact kvab [T][640]
      u16* kvab = (u16*)Cout;
#pragma unroll
      for (int m = 0; m < MFR; ++m)
#pragma unroll
        for (int n = 0; n < 4; ++n) {
          const int col = n0 - QDIM + wn + n * 16 + cc;
          const int trow = m0 + wm + m * 16 + r0w;
#pragma unroll
          for (int r = 0; r < 4; ++r)
            kvab[(size_t)(trow + r) * 640 + col] = f2b(acc[m][n][r]);
        }
    }
  } else {
#pragma unroll
    for (int m = 0; m < MFR; ++m)
#pragma unroll
      for (int n = 0; n < 4; ++n)
#pragma unroll
        for (int r = 0; r < 4; ++r) {
          const size_t idx = (size_t)(m0 + wm + m * 16 + r0w + r) * N + (n0 + wn + n * 16 + cc);
          ((float*)Cout)[idx] = acc[m][n][r];
        }
  }
}

// ---------------- fused post-qkva: rmsnorm(kv_c) + rope(k_pe)->kf bcast ----------
// reads compact kvab [T][640]
__global__ __launch_bounds__(256) void post_qkva(
    const u16* __restrict__ kvab, const float* __restrict__ lnw,
    const float* __restrict__ ctab, const float* __restrict__ stab,
    u16* __restrict__ kvc, u16* __restrict__ kf)
{
  const int t = blockIdx.x;
  const int tid = threadIdx.x;
  __shared__ float csh[32], ssh[32], wsum[4];
  __shared__ u16 kpesh[64];
  if (tid < 32) { csh[tid] = ctab[t * 32 + tid]; ssh[tid] = stab[t * 32 + tid]; }

  const u16* row = kvab + (size_t)t * 640;
  u16x2 v2 = *(const u16x2*)(row + tid * 2);
  float vx = b2f(v2.x), vy = b2f(v2.y);
  float ss = vx * vx + vy * vy;
#pragma unroll
  for (int d = 1; d < 64; d <<= 1) ss += __shfl_xor(ss, d, 64);
  if ((tid & 63) == 0) wsum[tid >> 6] = ss;
  __syncthreads();
  float tot = wsum[0] + wsum[1] + wsum[2] + wsum[3];
  float rs = rsqrtf(tot * (1.f / 512.f) + 1e-6f);
  float2 wv = *(const float2*)(lnw + tid * 2);
  kvc[(size_t)t * 512 + tid * 2]     = f2b(vx * rs * wv.x);
  kvc[(size_t)t * 512 + tid * 2 + 1] = f2b(vy * rs * wv.y);
  if (tid < 32) {
    float x1 = b2f(row[512 + 2 * tid]), x2 = b2f(row[513 + 2 * tid]);
    kpesh[2 * tid]     = f2b(x1 * csh[tid] - x2 * ssh[tid]);
    kpesh[2 * tid + 1] = f2b(x2 * csh[tid] + x1 * ssh[tid]);
  }
  __syncthreads();
  {
    const int h = tid >> 4, d0 = (tid & 15) * 4;
    u16x4 kp = *(const u16x4*)&kpesh[d0];
    *(u16x4*)&kf[(size_t)t * QDIM + h * DQK + 128 + d0] = kp;
  }
}

// ---------------- flash attention (causal), swapped QK^T, lane-scalar softmax -------
// grid: (16 heads, 40 chunk-tasks) — head on x so same-head blocks share an XCD L2.
__global__ __launch_bounds__(512) void attn_fwd(
    const u16* __restrict__ qf, const u16* __restrict__ kf,
    const u16* __restrict__ vT, u16* __restrict__ Opart,
    float* __restrict__ mpart, float* __restrict__ lpart)
{
  const int h = blockIdx.x;
  const int j = (TPH - 1) - blockIdx.y;    // biggest chunks dispatch first
  int qt, c, S;
  if (j < 4)       { qt = j;                c = 0;        S = 1; }
  else if (j < 12) { int u = j-4;  qt = 4 + (u>>1);  c = u&1;     S = 2; }
  else if (j < 24) { int u = j-12; int q3 = u/3; qt = 8+q3; c = u-3*q3; S = 3; }
  else             { int u = j-24; qt = 12 + (u>>2); c = u&3;     S = 4; }
  const int n = 2 * qt + 2;
  const int kt0 = (c * n) / S, kt1 = ((c + 1) * n) / S;
  const int task = h * TPH + j;
  const int q0 = qt * QBLK;

  const int tid = threadIdx.x;
  const int w = tid >> 6, lane = tid & 63;
  const int qw = q0 + w * 16;
  const int l15 = lane & 15, lh = lane >> 4;
  const int qrow = qw + l15;               // this lane's q (col of swapped C)

  __shared__ __align__(16) u16 Ks[KVBLK * 192];   // [64][384B] XOR-swizzled
  __shared__ __align__(16) u16 Vs[128 * 64];      // V^T tile [128 d][128B] XOR-swizzled
  __shared__ __align__(16) u16 P[8][16][72];      // per-wave P: [q=16][kv=64 pad 72]

  s16x8 aQ[6];
#pragma unroll
  for (int kg = 0; kg < 6; ++kg)
    aQ[kg] = *(const s16x8*)&qf[(size_t)qrow * QDIM + h * DQK + kg * 32 + lh * 8];

  f32x4 accO[8];
  const f32x4 zero = {0.f, 0.f, 0.f, 0.f};
#pragma unroll
  for (int vn = 0; vn < 8; ++vn) accO[vn] = zero;
  float mreg = NEG_INF, lreg = 0.f;        // scalar per lane (per q)

  const int rK = tid >> 3, cK = (tid & 7) * 16;
  const int rV = tid >> 2, cV = (tid & 3) * 16;
  const u16* gK = kf + (size_t)rK * QDIM + h * DQK;
  const u16* gV = vT + ((size_t)h * 128 + rV) * T_N;
  const int swK = (rK & 7) << 4;
  const int swV = (rV & 7) << 4;

  s16x8 stK[3], stV[2];
#pragma unroll
  for (int jj = 0; jj < 3; ++jj)
    stK[jj] = *(const s16x8*)((const char*)(gK + (size_t)(kt0 * KVBLK) * QDIM) + cK + jj * 128);
#pragma unroll
  for (int jj = 0; jj < 2; ++jj)
    stV[jj] = *(const s16x8*)((const char*)(gV + kt0 * KVBLK) + cV + jj * 64);

  for (int kt = kt0; kt < kt1; ++kt) {
    const int t0 = kt * KVBLK;
    __syncthreads();
#pragma unroll
    for (int jj = 0; jj < 3; ++jj)
      *(s16x8*)((char*)Ks + rK * 384 + ((cK + jj * 128) ^ swK)) = stK[jj];
#pragma unroll
    for (int jj = 0; jj < 2; ++jj)
      *(s16x8*)((char*)Vs + rV * 128 + ((cV + jj * 64) ^ swV)) = stV[jj];
    __syncthreads();
    if (kt + 1 < kt1) {
      const int tn = t0 + KVBLK;
#pragma unroll
      for (int jj = 0; jj < 3; ++jj)
        stK[jj] = *(const s16x8*)((const char*)(gK + (size_t)tn * QDIM) + cK + jj * 128);
#pragma unroll
      for (int jj = 0; jj < 2; ++jj)
        stV[jj] = *(const s16x8*)((const char*)(gV + tn) + cV + jj * 64);
    }

    // swapped QK^T: s[ct] = K_frag * Q_frag; C col = q (l15), row = kv-within-16
    f32x4 s[4];
#pragma unroll
    for (int ct = 0; ct < 4; ++ct) s[ct] = zero;
    const int swq = (l15 & 7) << 4;
    __builtin_amdgcn_s_setprio(1);
#pragma unroll
    for (int ct = 0; ct < 4; ++ct) {
      const char* kbase = (char*)Ks + (ct * 16 + l15) * 384;
#pragma unroll
      for (int kg = 0; kg < 6; ++kg) {
        s16x8 aK = *(const s16x8*)(kbase + ((kg * 64 + lh * 16) ^ swq));
        s[ct] = __builtin_amdgcn_mfma_f32_16x16x32_bf16(aK, aQ[kg], s[ct], 0, 0, 0);
      }
    }
    __builtin_amdgcn_s_setprio(0);

    const bool diag = (t0 + KVBLK > q0);
    if (diag) {
#pragma unroll
      for (int ct = 0; ct < 4; ++ct)
#pragma unroll
        for (int r = 0; r < 4; ++r)
          s[ct][r] = (t0 + ct * 16 + lh * 4 + r <= qrow) ? s[ct][r] : NEG_INF;
    }

    float mx = s[0][0];
#pragma unroll
    for (int ct = 0; ct < 4; ++ct)
#pragma unroll
      for (int r = 0; r < 4; ++r) mx = fmaxf(mx, s[ct][r]);
    mx = fmaxf(mx, __shfl_xor(mx, 16, 64));
    mx = fmaxf(mx, __shfl_xor(mx, 32, 64));
    if (mx > mreg + 8.f) {                 // defer-max (T13, THR=8)
      float sc = __expf(mreg - mx);
      lreg *= sc;
#pragma unroll
      for (int vn = 0; vn < 8; ++vn)
#pragma unroll
        for (int r = 0; r < 4; ++r) accO[vn][r] *= sc;
      mreg = mx;
    }
    float p[4][4];
    float ps = 0.f;
#pragma unroll
    for (int ct = 0; ct < 4; ++ct)
#pragma unroll
      for (int r = 0; r < 4; ++r) { p[ct][r] = __expf(s[ct][r] - mreg); ps += p[ct][r]; }
    ps += __shfl_xor(ps, 16, 64);
    ps += __shfl_xor(ps, 32, 64);
    lreg += ps;

#pragma unroll
    for (int ct = 0; ct < 4; ++ct) {
      u16x4 pk;
      pk.x = f2b(p[ct][0]); pk.y = f2b(p[ct][1]);
      pk.z = f2b(p[ct][2]); pk.w = f2b(p[ct][3]);
      *(u16x4*)&P[w][l15][ct * 16 + lh * 4] = pk;
    }
    asm volatile("s_waitcnt lgkmcnt(0)" ::: "memory");  // per-wave P visible
    s16x8 pb0 = *(const s16x8*)&P[w][l15][lh * 8];
    s16x8 pb1 = *(const s16x8*)&P[w][l15][32 + lh * 8];

    __builtin_amdgcn_s_setprio(1);
#pragma unroll
    for (int vn = 0; vn < 8; ++vn) {
      const char* vbase = (char*)Vs + (vn * 16 + l15) * 128;
      s16x8 aV0 = *(const s16x8*)(vbase + ((lh * 16) ^ swq));
      s16x8 aV1 = *(const s16x8*)(vbase + ((64 + lh * 16) ^ swq));
      accO[vn] = __builtin_amdgcn_mfma_f32_16x16x32_bf16(aV0, pb0, accO[vn], 0, 0, 0);
      accO[vn] = __builtin_amdgcn_mfma_f32_16x16x32_bf16(aV1, pb1, accO[vn], 0, 0, 0);
    }
    __builtin_amdgcn_s_setprio(0);
  }

  u16* Ob = Opart + ((size_t)task << 14);
  const int rl = w * 16 + l15;             // q-row within 128
#pragma unroll
  for (int vn = 0; vn < 8; ++vn) {
    u16x4 o;
    o.x = f2b(accO[vn][0]); o.y = f2b(accO[vn][1]);
    o.z = f2b(accO[vn][2]); o.w = f2b(accO[vn][3]);
    *(u16x4*)&Ob[rl * 128 + vn * 16 + lh * 4] = o;
  }
  if (lane < 16) {
    mpart[task * 128 + rl] = mreg;
    lpart[task * 128 + rl] = lreg;
  }
}

// ---------------- merge partial chunks -> attn output (bf16) ----------------
__global__ __launch_bounds__(256) void attn_merge(
    const u16* __restrict__ Opart, const float* __restrict__ mpart,
    const float* __restrict__ lpart, u16* __restrict__ attno)
{
  const int h = blockIdx.x >> 4, qt = blockIdx.x & 15;
  const int S = (qt >> 2) + 1;
  int base;
  if (qt < 4) base = qt; else if (qt < 8) base = 4 + 2*(qt-4);
  else if (qt < 12) base = 12 + 3*(qt-8); else base = 24 + 4*(qt-12);
  const int task0 = h * TPH + base;
  const int tid = threadIdx.x;
  __shared__ float wn[4][128];
  if (tid < 128) {
    float mc[4], lc[4];
    float M = NEG_INF;
    for (int c = 0; c < S; ++c) {
      mc[c] = mpart[(task0 + c) * 128 + tid];
      lc[c] = lpart[(task0 + c) * 128 + tid];
      M = fmaxf(M, mc[c]);
    }
    float L = 0.f, e[4];
    for (int c = 0; c < S; ++c) { e[c] = __expf(mc[c] - M); L += lc[c] * e[c]; }
    float Li = 1.f / L;
    for (int c = 0; c < S; ++c) wn[c][tid] = e[c] * Li;
  }
  __syncthreads();
  const int q0 = qt * QBLK;
#pragma unroll 4
  for (int k = 0; k < 16; ++k) {
    int bidx = k * 1024 + tid * 4;         // 4-element group
    int row = bidx >> 7, col = bidx & 127;
    float a0 = 0.f, a1 = 0.f, a2 = 0.f, a3 = 0.f;
    for (int c = 0; c < S; ++c) {
      u16x4 v = *(const u16x4*)&Opart[(((size_t)(task0 + c)) << 14) + bidx];
      float wgt = wn[c][row];
      a0 += wgt * b2f(v.x); a1 += wgt * b2f(v.y);
      a2 += wgt * b2f(v.z); a3 += wgt * b2f(v.w);
    }
    u16x4 o; o.x = f2b(a0); o.y = f2b(a1); o.z = f2b(a2); o.w = f2b(a3);
    *(u16x4*)&attno[(size_t)(q0 + row) * (NH * DV) + h * DV + col] = o;
  }
}

// ---------------- host launch ----------------
extern "C" void kernel_launch(void* const* d_in, const int* in_sizes, int n_in,
                              void* d_out, int out_size, void* d_ws, size_t ws_size,
                              hipStream_t stream)
{
  const int*   positions = (const int*)d_in[0];
  const float* hs    = (const float*)d_in[1];
  const float* w_q   = (const float*)d_in[2];
  const float* w_kva = (const float*)d_in[3];
  const float* lnw   = (const float*)d_in[4];
  const float* w_kvb = (const float*)d_in[5];
  const float* w_o   = (const float*)d_in[6];
  float* out = (float*)d_out;

  char* ws = (char*)d_ws;
  size_t off = 0;
  auto take = [&](size_t bytes) {
    char* p = ws + off;
    off += (bytes + 255) & ~(size_t)255;
    return p;
  };

  // persistent (live across attention)
  u16*   hsb  = (u16*)  take((size_t)T_N * HID * 2);       // reused as attn-out
  u16*   woT  = (u16*)  take((size_t)HID * (NH * DV) * 2);
  u16*   qfb  = (u16*)  take((size_t)T_N * QDIM * 2);
  u16*   kfb  = (u16*)  take((size_t)T_N * QDIM * 2);
  u16*   vTb  = (u16*)  take((size_t)NH * 128 * T_N * 2);
  float* ctab = (float*)take((size_t)T_N * 32 * 4);
  float* stab = (float*)take((size_t)T_N * 32 * 4);

  // union region: phase-A staging overlaid by phase-B attention partials
  size_t un0 = off;
  u16*   wqkvT = (u16*)  take((size_t)QKVN * HID * 2);     // fused [w_q^T; w_kva^T(pad640)]
  u16*   wkvbT = (u16*)  take((size_t)KVBD * KVD * 2);
  u16*   kvc   = (u16*)  take((size_t)T_N * KVD * 2);
  u16*   kvab  = (u16*)  take((size_t)T_N * 640 * 2);      // compact kv_a C (bf16)
  // phase-B overlay (all of the above dead at attn time)
  u16*   Opart = (u16*)(ws + un0);                         // 640 tasks * 16384 bf16
  float* mpart = (float*)(Opart + ((size_t)NH * TPH << 14));
  float* lpart = mpart + (size_t)NH * TPH * 128;
  u16*   attno = hsb;

  (void)positions; (void)in_sizes; (void)n_in; (void)out_size; (void)ws_size;

  prep_all<<<dim3(NBC + NBT + NB0), dim3(256), 0, stream>>>(
      hs, hsb, positions, ctab, stab, w_q, w_kva, wqkvT);

  // fused q-proj + kv_a GEMM (464 blocks, 128-tiles): q -> qf (rope+scale in epilogue),
  // kva -> compact kvab; + overflow transpose blocks (wkvb, wo)
  gemm_bf16<1, 128><<<dim3((T_N / 128) * (QKVN / 128) + NB1 + NB2), dim3(256), 0, stream>>>(
      hsb, wqkvT, kvab, nullptr, w_kvb, w_o, wkvbT, woT, ctab, stab, qfb, T_N, QKVN, HID);
  post_qkva<<<dim3(T_N), dim3(256), 0, stream>>>(kvab, lnw, ctab, stab, kvc, kfb);

  // kv_b with fused epilogue: 64-row M-tiles (1024 blocks, 4/CU)
  gemm_bf16<2, 64><<<dim3((T_N / 64) * (KVBD / 128)), dim3(256), 0, stream>>>(
      kvc, wkvbT, kfb, vTb, nullptr, nullptr, nullptr, nullptr, nullptr, nullptr, nullptr,
      T_N, KVBD, KVD);

  attn_fwd<<<dim3(NH, TPH), dim3(512), 0, stream>>>(qfb, kfb, vTb, Opart, mpart, lpart);
  attn_merge<<<dim3(NH * 16), dim3(256), 0, stream>>>(Opart, mpart, lpart, attno);

  // o-proj: 64-row M-tiles (512 blocks, 2/CU)
  gemm_bf16<0, 64><<<dim3((T_N / 64) * (HID / 128)), dim3(256), 0, stream>>>(
      attno, woT, out, nullptr, nullptr, nullptr, nullptr, nullptr, nullptr, nullptr, nullptr,
      T_N, HID, HID);
}

// Round 21
// 189.652 us; speedup vs baseline: 1.0078x; 1.0078x over previous
//
#include <hip/hip_runtime.h>
#include <hip/hip_bf16.h>
#include <stdint.h>

#define T_N  2048
#define HID  2048
#define NH   16
#define DN   128
#define DR   64
#define DV   128
#define KVD  512
#define DQK  192      // DN+DR
#define QDIM 3072     // NH*DQK
#define KVBD 4096     // NH*(DN+DV)
#define KVA  576      // KVD+DR
#define QKVN 3712     // fused q(3072) + kv_a(640 padded)
#define QBLK 128
#define KVBLK 64
#define TPH  40       // chunk-tasks per head

typedef short  s16x8 __attribute__((ext_vector_type(8)));
typedef float  f32x4 __attribute__((ext_vector_type(4)));
typedef unsigned short u16;
typedef unsigned short u16x2 __attribute__((ext_vector_type(2)));
typedef unsigned short u16x4 __attribute__((ext_vector_type(4)));

#define NEG_INF (-__builtin_inff())
#define AS1 __attribute__((address_space(1)))
#define AS3 __attribute__((address_space(3)))
__device__ __constant__ float SCALE_C = 0.07216878364870323f; // 192^-0.5

__device__ __forceinline__ u16 f2b(float f) {
  unsigned u = __float_as_uint(f);
  u += 0x7fffu + ((u >> 16) & 1u);
  return (u16)(u >> 16);
}
__device__ __forceinline__ float b2f(u16 v) {
  return __uint_as_float(((unsigned)v) << 16);
}

// ---------------- prep: hs cast + trig tables + wqkvT transpose ----------------
#define TQK (QKVN / 32)                          // 116
#define NBC 4096                                 // cast blocks
#define NBT 256                                  // table blocks
#define NB0 (TQK * (HID / 32))                   // 7424 (wqkvT)
#define NB1 ((KVBD / 32) * (KVD / 32))           // 2048 (wkvbT, fused into qkva GEMM)
#define NB2 ((HID / 32) * ((NH * DV) / 32))      // 4096 (woT, fused into qkva GEMM)
__global__ __launch_bounds__(256) void prep_all(
    const float* __restrict__ hs, u16* __restrict__ hsb,
    const int* __restrict__ pos, float* __restrict__ ctab, float* __restrict__ stab,
    const float* __restrict__ wq, const float* __restrict__ wkva,
    u16* __restrict__ wqkvT)
{
  int bid = blockIdx.x;
  const int tid = threadIdx.x;
  if (bid < NBC) {                       // cast: T_N*HID/4 float4 groups
    int i = bid * 256 + tid;
    float4 v = ((const float4*)hs)[i];
    u16x4 o;
    o.x = f2b(v.x); o.y = f2b(v.y); o.z = f2b(v.z); o.w = f2b(v.w);
    ((u16x4*)hsb)[i] = o;
    return;
  }
  if (bid < NBC + NBT) {                 // tables: T_N*32 entries
    int i = (bid - NBC) * 256 + tid;
    int t = i >> 5, j = i & 31;
    float inv = powf(10000.f, -(float)(2 * j) / 64.f);
    float f = (float)pos[t] * inv;
    float s, c;
    sincosf(f, &s, &c);
    ctab[i] = c; stab[i] = s;
    return;
  }
  bid -= NBC + NBT;                      // wqkvT transpose
  __shared__ float tile[32][33];
  const int tx = tid & 31, ty = tid >> 5;
  const int n0 = (bid % TQK) * 32, k0 = (bid / TQK) * 32;
#pragma unroll
  for (int i = 0; i < 4; ++i) {
    const int n = n0 + tx, k = k0 + ty + i * 8;
    float val;
    if (n < QDIM) val = wq[(size_t)k * QDIM + n];
    else { int n2 = n - QDIM; val = (n2 < KVA) ? wkva[(size_t)k * KVA + n2] : 0.f; }
    tile[ty + i * 8][tx] = val;
  }
  __syncthreads();
#pragma unroll
  for (int i = 0; i < 4; ++i)
    wqkvT[(size_t)(n0 + ty + i * 8) * HID + k0 + tx] = f2b(tile[tx][ty + i * 8]);
}

// ---------------- bf16 GEMM: TM x 128 tiles, BK=32 double-buffered, swizzled LDS ----
// MODE 0: C float. MODE 1: qkva — q cols roped+scaled straight to qf, kva cols to
//         compact kvab[T][640]; + overflow transpose blocks (wkvb->wkvbT, wo->woT).
// MODE 2: kv_b epilogue -> kf (nope half) + vT (v half). TM = 128 or 64 (M-tile).
// Tile decode is M-fastest within XCD id chunks: B-tile stays L2-hot, A streams (L3).
template <int MODE, int TM>
__global__ __launch_bounds__(256) void gemm_bf16(
    const u16* __restrict__ A, const u16* __restrict__ Bt,
    void* __restrict__ Cout, u16* __restrict__ vT,
    const float* __restrict__ xw1, const float* __restrict__ xw2,
    u16* __restrict__ xd1, u16* __restrict__ xd2,
    const float* __restrict__ ctp, const float* __restrict__ stp,
    u16* __restrict__ qfo,
    int M, int N, int K)
{
  constexpr int ASZ = TM * 32;                     // A-buf u16 count (2048 or 4096)
  constexpr int MFR = TM / 32;                     // m-frags per wave (2 or 4)
  __shared__ __align__(16) u16 LDSu[2][ASZ + 4096];
  const int tid  = threadIdx.x;
  const int gx   = N >> 7;
  const int gy   = M / TM;
  const int nwg  = gy * gx;

  if constexpr (MODE == 1) {
    // overflow blocks: wkvb / wo transposes, run on spare CUs while GEMM computes
    if ((int)blockIdx.x >= nwg) {
      float (*tile)[33] = reinterpret_cast<float(*)[33]>(&LDSu[0][0]);
      int b = (int)blockIdx.x - nwg;
      const float* src; u16* dst; int n0t, k0t, Kt, Nt;
      if (b < NB1) { n0t = (b % (KVBD/32)) * 32; k0t = (b / (KVBD/32)) * 32; Kt = KVD;   Nt = KVBD; src = xw1; dst = xd1; }
      else { b -= NB1; n0t = (b % (HID/32)) * 32;  k0t = (b / (HID/32)) * 32;  Kt = NH*DV; Nt = HID;  src = xw2; dst = xd2; }
      const int tx = tid & 31, ty = tid >> 5;
#pragma unroll
      for (int i = 0; i < 4; ++i)
        tile[ty + i * 8][tx] = src[(size_t)(k0t + ty + i * 8) * Nt + n0t + tx];
      __syncthreads();
#pragma unroll
      for (int i = 0; i < 4; ++i)
        dst[(size_t)(n0t + ty + i * 8) * Kt + k0t + tx] = f2b(tile[tx][ty + i * 8]);
      return;
    }
  }

  const int lane = tid & 63;
  const int w    = tid >> 6;
  int id = blockIdx.x;
  id = (id & 7) * (nwg >> 3) + (id >> 3);           // bijective XCD swizzle (nwg%8==0)
  const int m0 = (id % gy) * TM, n0 = (id / gy) * 128;   // M-fastest within XCD chunk

  const int wm = (w >> 1) * (TM / 2), wn = (w & 1) * 64;

  const int r0   = tid >> 2;                          // 0..63
  const int selE = (((tid & 3) ^ (r0 & 3)) << 3);     // element col within 32
  const u16* sA = A  + (size_t)(m0 + r0) * K + selE;
  const u16* sB = Bt + (size_t)(n0 + r0) * K + selE;
  const int ldsOff = tid * 8;                          // u16 units

  f32x4 acc[MFR][4];
  const f32x4 zero = {0.f, 0.f, 0.f, 0.f};
#pragma unroll
  for (int m = 0; m < MFR; ++m)
#pragma unroll
    for (int n = 0; n < 4; ++n) acc[m][n] = zero;

  const int arow = lane & 15;
  const int kb   = (lane >> 4) * 16;
  const int KT = K >> 5;

  auto stage = [&](int buf, int kt) {
    const int ko = kt << 5;
#pragma unroll
    for (int j = 0; j < TM / 64; ++j)
      __builtin_amdgcn_global_load_lds((const AS1 unsigned*)(sA + ko + (size_t)j * 64 * K),
                                       (AS3 unsigned*)(&LDSu[buf][ldsOff + j * 2048]), 16, 0, 0);
#pragma unroll
    for (int j = 0; j < 2; ++j)
      __builtin_amdgcn_global_load_lds((const AS1 unsigned*)(sB + ko + (size_t)j * 64 * K),
                                       (AS3 unsigned*)(&LDSu[buf][ASZ + ldsOff + j * 2048]), 16, 0, 0);
  };
  auto compute = [&](int buf) {
    const char* Ab = (const char*)&LDSu[buf][0];
    const char* Bb = (const char*)&LDSu[buf][ASZ];
    s16x8 af[MFR], bfr[4];
#pragma unroll
    for (int m = 0; m < MFR; ++m) {
      const int r = wm + m * 16 + arow;
      af[m] = *(const s16x8*)(Ab + r * 64 + (kb ^ ((r & 3) << 4)));
    }
#pragma unroll
    for (int n = 0; n < 4; ++n) {
      const int r = wn + n * 16 + arow;
      bfr[n] = *(const s16x8*)(Bb + r * 64 + (kb ^ ((r & 3) << 4)));
    }
#pragma unroll
    for (int m = 0; m < MFR; ++m)
#pragma unroll
      for (int n = 0; n < 4; ++n)
        acc[m][n] = __builtin_amdgcn_mfma_f32_16x16x32_bf16(af[m], bfr[n], acc[m][n], 0, 0, 0);
  };

  stage(0, 0);
  for (int kt = 0; kt < KT; kt += 2) {
    __syncthreads();
    stage(1, kt + 1);
    compute(0);
    __syncthreads();
    if (kt + 2 < KT) stage(0, kt + 2);
    compute(1);
  }

  const int r0w = (lane >> 4) * 4;
  const int cc = lane & 15;
  if constexpr (MODE == 2) {
    const int h = n0 >> 8;
    const bool vhalf = (n0 >> 7) & 1;
    u16* kf = (u16*)Cout;
#pragma unroll
    for (int m = 0; m < MFR; ++m)
#pragma unroll
      for (int n = 0; n < 4; ++n) {
        const int d = wn + n * 16 + cc;
        const int trow = m0 + wm + m * 16 + r0w;
        if (!vhalf) {
#pragma unroll
          for (int r = 0; r < 4; ++r)
            kf[(size_t)(trow + r) * QDIM + h * DQK + d] = f2b(acc[m][n][r]);
        } else {
          u16x4 o;
          o.x = f2b(acc[m][n][0]); o.y = f2b(acc[m][n][1]);
          o.z = f2b(acc[m][n][2]); o.w = f2b(acc[m][n][3]);
          *(u16x4*)&vT[((size_t)h * 128 + d) * T_N + trow] = o;
        }
      }
  } else if constexpr (MODE == 1) {
    if (n0 < QDIM) {
      // q region: rope (pe cols, pair via adjacent-lane shfl) + scale -> qf
      const float SC = SCALE_C;
#pragma unroll
      for (int m = 0; m < MFR; ++m)
#pragma unroll
        for (int n = 0; n < 4; ++n) {
          const int col = n0 + wn + n * 16 + cc;
          const int hh = col / DQK;
          const int d  = col - hh * DQK;
          const int trow = m0 + wm + m * 16 + r0w;
          if (d < 128) {
#pragma unroll
            for (int r = 0; r < 4; ++r)
              qfo[((size_t)(trow + r) * NH + hh) * DQK + d] = f2b(acc[m][n][r] * SC);
          } else {
            const int jj = (d - 128) >> 1;
            const float sgn = (d & 1) ? 1.f : -1.f;   // pairs never straddle d=128/head edge
#pragma unroll
            for (int r = 0; r < 4; ++r) {
              float v  = acc[m][n][r];
              float vp = __shfl_xor(v, 1, 64);        // partner col (even<->odd)
              const int t = trow + r;
              float cv = ctp[t * 32 + jj], sv = stp[t * 32 + jj];
              qfo[((size_t)t * NH + hh) * DQK + d] = f2b((v * cv + sgn * vp * sv) * SC);
            }
          }
        }
    } else {
      // kva region -> compact kvab [T][640]
      u16* kvab = (u16*)Cout;
#pragma unroll
      for (int m = 0; m < MFR; ++m)
#pragma unroll
        for (int n = 0; n < 4; ++n) {
          const int col = n0 - QDIM + wn + n * 16 + cc;
          const int trow = m0 + wm + m * 16 + r0w;
#pragma unroll
          for (int r = 0; r < 4; ++r)
            kvab[(size_t)(trow + r) * 640 + col] = f2b(acc[m][n][r]);
        }
    }
  } else {
#pragma unroll
    for (int m = 0; m < MFR; ++m)
#pragma unroll
      for (int n = 0; n < 4; ++n)
#pragma unroll
        for (int r = 0; r < 4; ++r) {
          const size_t idx = (size_t)(m0 + wm + m * 16 + r0w + r) * N + (n0 + wn + n * 16 + cc);
          ((float*)Cout)[idx] = acc[m][n][r];
        }
  }
}

// ---------------- fused post-qkva: rmsnorm(kv_c) + rope(k_pe)->kf bcast ----------
// reads compact kvab [T][640]
__global__ __launch_bounds__(256) void post_qkva(
    const u16* __restrict__ kvab, const float* __restrict__ lnw,
    const float* __restrict__ ctab, const float* __restrict__ stab,
    u16* __restrict__ kvc, u16* __restrict__ kf)
{
  const int t = blockIdx.x;
  const int tid = threadIdx.x;
  __shared__ float csh[32], ssh[32], wsum[4];
  __shared__ u16 kpesh[64];
  if (tid < 32) { csh[tid] = ctab[t * 32 + tid]; ssh[tid] = stab[t * 32 + tid]; }

  const u16* row = kvab + (size_t)t * 640;
  u16x2 v2 = *(const u16x2*)(row + tid * 2);
  float vx = b2f(v2.x), vy = b2f(v2.y);
  float ss = vx * vx + vy * vy;
#pragma unroll
  for (int d = 1; d < 64; d <<= 1) ss += __shfl_xor(ss, d, 64);
  if ((tid & 63) == 0) wsum[tid >> 6] = ss;
  __syncthreads();
  float tot = wsum[0] + wsum[1] + wsum[2] + wsum[3];
  float rs = rsqrtf(tot * (1.f / 512.f) + 1e-6f);
  float2 wv = *(const float2*)(lnw + tid * 2);
  kvc[(size_t)t * 512 + tid * 2]     = f2b(vx * rs * wv.x);
  kvc[(size_t)t * 512 + tid * 2 + 1] = f2b(vy * rs * wv.y);
  if (tid < 32) {
    float x1 = b2f(row[512 + 2 * tid]), x2 = b2f(row[513 + 2 * tid]);
    kpesh[2 * tid]     = f2b(x1 * csh[tid] - x2 * ssh[tid]);
    kpesh[2 * tid + 1] = f2b(x2 * csh[tid] + x1 * ssh[tid]);
  }
  __syncthreads();
  {
    const int h = tid >> 4, d0 = (tid & 15) * 4;
    u16x4 kp = *(const u16x4*)&kpesh[d0];
    *(u16x4*)&kf[(size_t)t * QDIM + h * DQK + 128 + d0] = kp;
  }
}

// ---------------- flash attention (causal), swapped QK^T, lane-scalar softmax -------
// grid: (16 heads, 40 chunk-tasks) — head on x so same-head blocks share an XCD L2.
__global__ __launch_bounds__(512) void attn_fwd(
    const u16* __restrict__ qf, const u16* __restrict__ kf,
    const u16* __restrict__ vT, u16* __restrict__ Opart,
    float* __restrict__ mpart, float* __restrict__ lpart)
{
  const int h = blockIdx.x;
  const int j = (TPH - 1) - blockIdx.y;    // biggest chunks dispatch first
  int qt, c, S;
  if (j < 4)       { qt = j;                c = 0;        S = 1; }
  else if (j < 12) { int u = j-4;  qt = 4 + (u>>1);  c = u&1;     S = 2; }
  else if (j < 24) { int u = j-12; int q3 = u/3; qt = 8+q3; c = u-3*q3; S = 3; }
  else             { int u = j-24; qt = 12 + (u>>2); c = u&3;     S = 4; }
  const int n = 2 * qt + 2;
  const int kt0 = (c * n) / S, kt1 = ((c + 1) * n) / S;
  const int task = h * TPH + j;
  const int q0 = qt * QBLK;

  const int tid = threadIdx.x;
  const int w = tid >> 6, lane = tid & 63;
  const int qw = q0 + w * 16;
  const int l15 = lane & 15, lh = lane >> 4;
  const int qrow = qw + l15;               // this lane's q (col of swapped C)

  __shared__ __align__(16) u16 Ks[KVBLK * 192];   // [64][384B] XOR-swizzled
  __shared__ __align__(16) u16 Vs[128 * 64];      // V^T tile [128 d][128B] XOR-swizzled
  __shared__ __align__(16) u16 P[8][16][72];      // per-wave P: [q=16][kv=64 pad 72]

  s16x8 aQ[6];
#pragma unroll
  for (int kg = 0; kg < 6; ++kg)
    aQ[kg] = *(const s16x8*)&qf[(size_t)qrow * QDIM + h * DQK + kg * 32 + lh * 8];

  f32x4 accO[8];
  const f32x4 zero = {0.f, 0.f, 0.f, 0.f};
#pragma unroll
  for (int vn = 0; vn < 8; ++vn) accO[vn] = zero;
  float mreg = NEG_INF, lreg = 0.f;        // scalar per lane (per q)

  const int rK = tid >> 3, cK = (tid & 7) * 16;
  const int rV = tid >> 2, cV = (tid & 3) * 16;
  const u16* gK = kf + (size_t)rK * QDIM + h * DQK;
  const u16* gV = vT + ((size_t)h * 128 + rV) * T_N;
  const int swK = (rK & 7) << 4;
  const int swV = (rV & 7) << 4;

  s16x8 stK[3], stV[2];
#pragma unroll
  for (int jj = 0; jj < 3; ++jj)
    stK[jj] = *(const s16x8*)((const char*)(gK + (size_t)(kt0 * KVBLK) * QDIM) + cK + jj * 128);
#pragma unroll
  for (int jj = 0; jj < 2; ++jj)
    stV[jj] = *(const s16x8*)((const char*)(gV + kt0 * KVBLK) + cV + jj * 64);

  for (int kt = kt0; kt < kt1; ++kt) {
    const int t0 = kt * KVBLK;
    __syncthreads();
#pragma unroll
    for (int jj = 0; jj < 3; ++jj)
      *(s16x8*)((char*)Ks + rK * 384 + ((cK + jj * 128) ^ swK)) = stK[jj];
#pragma unroll
    for (int jj = 0; jj < 2; ++jj)
      *(s16x8*)((char*)Vs + rV * 128 + ((cV + jj * 64) ^ swV)) = stV[jj];
    __syncthreads();
    if (kt + 1 < kt1) {
      const int tn = t0 + KVBLK;
#pragma unroll
      for (int jj = 0; jj < 3; ++jj)
        stK[jj] = *(const s16x8*)((const char*)(gK + (size_t)tn * QDIM) + cK + jj * 128);
#pragma unroll
      for (int jj = 0; jj < 2; ++jj)
        stV[jj] = *(const s16x8*)((const char*)(gV + tn) + cV + jj * 64);
    }

    // swapped QK^T: s[ct] = K_frag * Q_frag; C col = q (l15), row = kv-within-16
    f32x4 s[4];
#pragma unroll
    for (int ct = 0; ct < 4; ++ct) s[ct] = zero;
    const int swq = (l15 & 7) << 4;
    __builtin_amdgcn_s_setprio(1);
#pragma unroll
    for (int ct = 0; ct < 4; ++ct) {
      const char* kbase = (char*)Ks + (ct * 16 + l15) * 384;
#pragma unroll
      for (int kg = 0; kg < 6; ++kg) {
        s16x8 aK = *(const s16x8*)(kbase + ((kg * 64 + lh * 16) ^ swq));
        s[ct] = __builtin_amdgcn_mfma_f32_16x16x32_bf16(aK, aQ[kg], s[ct], 0, 0, 0);
      }
    }
    __builtin_amdgcn_s_setprio(0);

    const bool diag = (t0 + KVBLK > q0);
    if (diag) {
#pragma unroll
      for (int ct = 0; ct < 4; ++ct)
#pragma unroll
        for (int r = 0; r < 4; ++r)
          s[ct][r] = (t0 + ct * 16 + lh * 4 + r <= qrow) ? s[ct][r] : NEG_INF;
    }

    float mx = s[0][0];
#pragma unroll
    for (int ct = 0; ct < 4; ++ct)
#pragma unroll
      for (int r = 0; r < 4; ++r) mx = fmaxf(mx, s[ct][r]);
    mx = fmaxf(mx, __shfl_xor(mx, 16, 64));
    mx = fmaxf(mx, __shfl_xor(mx, 32, 64));
    if (mx > mreg + 8.f) {                 // defer-max (T13, THR=8)
      float sc = __expf(mreg - mx);
      lreg *= sc;
#pragma unroll
      for (int vn = 0; vn < 8; ++vn)
#pragma unroll
        for (int r = 0; r < 4; ++r) accO[vn][r] *= sc;
      mreg = mx;
    }
    float p[4][4];
    float ps = 0.f;
#pragma unroll
    for (int ct = 0; ct < 4; ++ct)
#pragma unroll
      for (int r = 0; r < 4; ++r) { p[ct][r] = __expf(s[ct][r] - mreg); ps += p[ct][r]; }
    ps += __shfl_xor(ps, 16, 64);
    ps += __shfl_xor(ps, 32, 64);
    lreg += ps;

#pragma unroll
    for (int ct = 0; ct < 4; ++ct) {
      u16x4 pk;
      pk.x = f2b(p[ct][0]); pk.y = f2b(p[ct][1]);
      pk.z = f2b(p[ct][2]); pk.w = f2b(p[ct][3]);
      *(u16x4*)&P[w][l15][ct * 16 + lh * 4] = pk;
    }
    asm volatile("s_waitcnt lgkmcnt(0)" ::: "memory");  // per-wave P visible
    s16x8 pb0 = *(const s16x8*)&P[w][l15][lh * 8];
    s16x8 pb1 = *(const s16x8*)&P[w][l15][32 + lh * 8];

    __builtin_amdgcn_s_setprio(1);
#pragma unroll
    for (int vn = 0; vn < 8; ++vn) {
      const char* vbase = (char*)Vs + (vn * 16 + l15) * 128;
      s16x8 aV0 = *(const s16x8*)(vbase + ((lh * 16) ^ swq));
      s16x8 aV1 = *(const s16x8*)(vbase + ((64 + lh * 16) ^ swq));
      accO[vn] = __builtin_amdgcn_mfma_f32_16x16x32_bf16(aV0, pb0, accO[vn], 0, 0, 0);
      accO[vn] = __builtin_amdgcn_mfma_f32_16x16x32_bf16(aV1, pb1, accO[vn], 0, 0, 0);
    }
    __builtin_amdgcn_s_setprio(0);
  }

  u16* Ob = Opart + ((size_t)task << 14);
  const int rl = w * 16 + l15;             // q-row within 128
#pragma unroll
  for (int vn = 0; vn < 8; ++vn) {
    u16x4 o;
    o.x = f2b(accO[vn][0]); o.y = f2b(accO[vn][1]);
    o.z = f2b(accO[vn][2]); o.w = f2b(accO[vn][3]);
    *(u16x4*)&Ob[rl * 128 + vn * 16 + lh * 4] = o;
  }
  if (lane < 16) {
    mpart[task * 128 + rl] = mreg;
    lpart[task * 128 + rl] = lreg;
  }
}

// ---------------- merge partial chunks -> attn output (bf16) ----------------
__global__ __launch_bounds__(256) void attn_merge(
    const u16* __restrict__ Opart, const float* __restrict__ mpart,
    const float* __restrict__ lpart, u16* __restrict__ attno)
{
  const int h = blockIdx.x >> 4, qt = blockIdx.x & 15;
  const int S = (qt >> 2) + 1;
  int base;
  if (qt < 4) base = qt; else if (qt < 8) base = 4 + 2*(qt-4);
  else if (qt < 12) base = 12 + 3*(qt-8); else base = 24 + 4*(qt-12);
  const int task0 = h * TPH + base;
  const int tid = threadIdx.x;
  __shared__ float wn[4][128];
  if (tid < 128) {
    float mc[4], lc[4];
    float M = NEG_INF;
    for (int c = 0; c < S; ++c) {
      mc[c] = mpart[(task0 + c) * 128 + tid];
      lc[c] = lpart[(task0 + c) * 128 + tid];
      M = fmaxf(M, mc[c]);
    }
    float L = 0.f, e[4];
    for (int c = 0; c < S; ++c) { e[c] = __expf(mc[c] - M); L += lc[c] * e[c]; }
    float Li = 1.f / L;
    for (int c = 0; c < S; ++c) wn[c][tid] = e[c] * Li;
  }
  __syncthreads();
  const int q0 = qt * QBLK;
#pragma unroll 4
  for (int k = 0; k < 16; ++k) {
    int bidx = k * 1024 + tid * 4;         // 4-element group
    int row = bidx >> 7, col = bidx & 127;
    float a0 = 0.f, a1 = 0.f, a2 = 0.f, a3 = 0.f;
    for (int c = 0; c < S; ++c) {
      u16x4 v = *(const u16x4*)&Opart[(((size_t)(task0 + c)) << 14) + bidx];
      float wgt = wn[c][row];
      a0 += wgt * b2f(v.x); a1 += wgt * b2f(v.y);
      a2 += wgt * b2f(v.z); a3 += wgt * b2f(v.w);
    }
    u16x4 o; o.x = f2b(a0); o.y = f2b(a1); o.z = f2b(a2); o.w = f2b(a3);
    *(u16x4*)&attno[(size_t)(q0 + row) * (NH * DV) + h * DV + col] = o;
  }
}

// ---------------- host launch ----------------
extern "C" void kernel_launch(void* const* d_in, const int* in_sizes, int n_in,
                              void* d_out, int out_size, void* d_ws, size_t ws_size,
                              hipStream_t stream)
{
  const int*   positions = (const int*)d_in[0];
  const float* hs    = (const float*)d_in[1];
  const float* w_q   = (const float*)d_in[2];
  const float* w_kva = (const float*)d_in[3];
  const float* lnw   = (const float*)d_in[4];
  const float* w_kvb = (const float*)d_in[5];
  const float* w_o   = (const float*)d_in[6];
  float* out = (float*)d_out;

  char* ws = (char*)d_ws;
  size_t off = 0;
  auto take = [&](size_t bytes) {
    char* p = ws + off;
    off += (bytes + 255) & ~(size_t)255;
    return p;
  };

  // persistent (live across attention)
  u16*   hsb  = (u16*)  take((size_t)T_N * HID * 2);       // reused as attn-out
  u16*   woT  = (u16*)  take((size_t)HID * (NH * DV) * 2);
  u16*   qfb  = (u16*)  take((size_t)T_N * QDIM * 2);
  u16*   kfb  = (u16*)  take((size_t)T_N * QDIM * 2);
  u16*   vTb  = (u16*)  take((size_t)NH * 128 * T_N * 2);
  float* ctab = (float*)take((size_t)T_N * 32 * 4);
  float* stab = (float*)take((size_t)T_N * 32 * 4);

  // union region: phase-A staging overlaid by phase-B attention partials
  size_t un0 = off;
  u16*   wqkvT = (u16*)  take((size_t)QKVN * HID * 2);     // fused [w_q^T; w_kva^T(pad640)]
  u16*   wkvbT = (u16*)  take((size_t)KVBD * KVD * 2);
  u16*   kvc   = (u16*)  take((size_t)T_N * KVD * 2);
  u16*   kvab  = (u16*)  take((size_t)T_N * 640 * 2);      // compact kv_a C (bf16)
  // phase-B overlay (all of the above dead at attn time)
  u16*   Opart = (u16*)(ws + un0);                         // 640 tasks * 16384 bf16
  float* mpart = (float*)(Opart + ((size_t)NH * TPH << 14));
  float* lpart = mpart + (size_t)NH * TPH * 128;
  u16*   attno = hsb;

  (void)positions; (void)in_sizes; (void)n_in; (void)out_size; (void)ws_size;

  prep_all<<<dim3(NBC + NBT + NB0), dim3(256), 0, stream>>>(
      hs, hsb, positions, ctab, stab, w_q, w_kva, wqkvT);

  // fused q-proj + kv_a GEMM (464 blocks, 128-tiles): q -> qf (rope+scale in epilogue),
  // kva -> compact kvab; + overflow transpose blocks (wkvb, wo)
  gemm_bf16<1, 128><<<dim3((T_N / 128) * (QKVN / 128) + NB1 + NB2), dim3(256), 0, stream>>>(
      hsb, wqkvT, kvab, nullptr, w_kvb, w_o, wkvbT, woT, ctab, stab, qfb, T_N, QKVN, HID);
  post_qkva<<<dim3(T_N), dim3(256), 0, stream>>>(kvab, lnw, ctab, stab, kvc, kfb);

  // kv_b with fused epilogue: 64-row M-tiles (1024 blocks, 4/CU)
  gemm_bf16<2, 64><<<dim3((T_N / 64) * (KVBD / 128)), dim3(256), 0, stream>>>(
      kvc, wkvbT, kfb, vTb, nullptr, nullptr, nullptr, nullptr, nullptr, nullptr, nullptr,
      T_N, KVBD, KVD);

  attn_fwd<<<dim3(NH, TPH), dim3(512), 0, stream>>>(qfb, kfb, vTb, Opart, mpart, lpart);
  attn_merge<<<dim3(NH * 16), dim3(256), 0, stream>>>(Opart, mpart, lpart, attno);

  // o-proj: 64-row M-tiles (512 blocks, 2/CU)
  gemm_bf16<0, 64><<<dim3((T_N / 64) * (HID / 128)), dim3(256), 0, stream>>>(
      attno, woT, out, nullptr, nullptr, nullptr, nullptr, nullptr, nullptr, nullptr, nullptr,
      T_N, HID, HID);
}